// Round 1
// baseline (4030.176 us; speedup 1.0000x reference)
//
#include <hip/hip_runtime.h>

// SpatialSelfAttention: GroupNorm(16) -> q,k,v 1x1 conv -> softmax attention -> proj + residual
// B=8, C=256, H=W=64, N=4096. All fp32 (round-0 correctness-first baseline).

#define B_ 8
#define C_ 256
#define NPIX 4096
#define G_ 16

// ---------------- GroupNorm stats: one block per (b,g) ----------------
__global__ __launch_bounds__(256)
void gn_stats_k(const float4* __restrict__ x4, float* __restrict__ stats) {
  const int bg = blockIdx.x;                       // b*16+g
  const float4* xp = x4 + (size_t)bg * (16 * NPIX / 4);   // 16 channels contiguous
  float s = 0.f, ss = 0.f;
  for (int i = threadIdx.x; i < 16 * NPIX / 4; i += 256) {
    float4 v = xp[i];
    s  += v.x + v.y + v.z + v.w;
    ss += v.x * v.x + v.y * v.y + v.z * v.z + v.w * v.w;
  }
  #pragma unroll
  for (int off = 32; off > 0; off >>= 1) {
    s  += __shfl_down(s, off);
    ss += __shfl_down(ss, off);
  }
  __shared__ float sm[4], sm2[4];
  const int lane = threadIdx.x & 63, wid = threadIdx.x >> 6;
  if (lane == 0) { sm[wid] = s; sm2[wid] = ss; }
  __syncthreads();
  if (threadIdx.x == 0) {
    s  = sm[0] + sm[1] + sm[2] + sm[3];
    ss = sm2[0] + sm2[1] + sm2[2] + sm2[3];
    float mean = s * (1.f / 65536.f);
    float var  = ss * (1.f / 65536.f) - mean * mean;
    stats[bg * 2 + 0] = mean;
    stats[bg * 2 + 1] = rsqrtf(var + 1e-6f);
  }
}

// ---------------- apply GroupNorm -> hn ----------------
__global__ __launch_bounds__(256)
void gn_apply_k(const float4* __restrict__ x4, const float* __restrict__ stats,
                const float* __restrict__ gamma, const float* __restrict__ beta,
                float4* __restrict__ hn4) {
  const size_t total4 = (size_t)B_ * C_ * NPIX / 4;
  for (size_t p = (size_t)blockIdx.x * blockDim.x + threadIdx.x; p < total4;
       p += (size_t)gridDim.x * blockDim.x) {
    const size_t flat = p << 2;
    const int c  = (int)((flat >> 12) & (C_ - 1));
    const int bi = (int)(flat >> 20);
    const int sg = (bi * G_ + (c >> 4)) * 2;
    const float mean = stats[sg], rstd = stats[sg + 1];
    const float scl = rstd * gamma[c];
    const float sh  = beta[c] - mean * scl;
    float4 xv = x4[p];
    float4 r;
    r.x = xv.x * scl + sh; r.y = xv.y * scl + sh;
    r.z = xv.z * scl + sh; r.w = xv.w * scl + sh;
    hn4[p] = r;
  }
}

// ---------------- 1x1 conv GEMM: dst[b,o,n] = bias[o] + sum_c W[o,c]*src[b,c,n] (+resid) ----------------
// grid (N/64, C/64, B), 256 threads, 64x64 tile, BK=16, 4x4 per thread
__global__ __launch_bounds__(256)
void gemm1x1_k(const float* __restrict__ W, const float* __restrict__ bias,
               const float* __restrict__ src, const float* __restrict__ resid,
               float* __restrict__ dst) {
  const int b  = blockIdx.z;
  const int n0 = blockIdx.x * 64;
  const int o0 = blockIdx.y * 64;
  __shared__ float sA[16][68];   // sA[c][o]
  __shared__ float sB[16][68];   // sB[c][n]
  const int t  = threadIdx.x;
  const int tx = t & 15, ty = t >> 4;
  const int ca = t & 15, oa = t >> 4;   // A-load coords
  const int nb = t & 63, cb = t >> 6;   // B-load coords
  const float* srcb = src + (size_t)b * C_ * NPIX;
  float acc[4][4] = {};
  for (int c0 = 0; c0 < C_; c0 += 16) {
    #pragma unroll
    for (int p = 0; p < 4; ++p)
      sA[ca][oa + p * 16] = W[(size_t)(o0 + oa + p * 16) * C_ + c0 + ca];
    #pragma unroll
    for (int p = 0; p < 4; ++p)
      sB[cb + p * 4][nb] = srcb[(size_t)(c0 + cb + p * 4) * NPIX + n0 + nb];
    __syncthreads();
    #pragma unroll
    for (int c = 0; c < 16; ++c) {
      const float4 a  = *(const float4*)&sA[c][ty * 4];
      const float4 bb = *(const float4*)&sB[c][tx * 4];
      const float av[4] = {a.x, a.y, a.z, a.w};
      const float bv[4] = {bb.x, bb.y, bb.z, bb.w};
      #pragma unroll
      for (int m = 0; m < 4; ++m)
        #pragma unroll
        for (int n = 0; n < 4; ++n)
          acc[m][n] += av[m] * bv[n];
    }
    __syncthreads();
  }
  float* dstb = dst + (size_t)b * C_ * NPIX;
  const float* resb = resid ? resid + (size_t)b * C_ * NPIX : nullptr;
  #pragma unroll
  for (int m = 0; m < 4; ++m) {
    const int o = o0 + ty * 4 + m;
    const float bi = bias[o];
    const size_t base = (size_t)o * NPIX + n0 + tx * 4;
    float4 r;
    r.x = acc[m][0] + bi; r.y = acc[m][1] + bi;
    r.z = acc[m][2] + bi; r.w = acc[m][3] + bi;
    if (resb) {
      const float4 rv = *(const float4*)&resb[base];
      r.x += rv.x; r.y += rv.y; r.z += rv.z; r.w += rv.w;
    }
    *(float4*)&dstb[base] = r;
  }
}

// ---------------- flash attention fp32 ----------------
// block: 256 threads, BI=32 queries; iterate BJ=32 key tiles with online softmax.
// out[b,c,i] = (1/l_i) * sum_j exp(q.k/16 - m_i) * v[c,j]
__global__ __launch_bounds__(256)
void attn_k(const float* __restrict__ q, const float* __restrict__ k,
            const float* __restrict__ v, float* __restrict__ out) {
  const int bid = blockIdx.x;
  const int b  = bid & 7;            // XCD-swizzle: batch b pinned to XCD (bid%8)
  const int i0 = (bid >> 3) * 32;
  const size_t boff = (size_t)b * C_ * NPIX;
  const float* qb = q + boff;
  const float* kb = k + boff;
  const float* vb = v + boff;

  __shared__ float Qs[C_][33];
  __shared__ float KV[C_][33];
  __shared__ float Ps[32][33];
  __shared__ float mrow[32], lrow[32], srow[32];

  const int t  = threadIdx.x;
  const int li = t & 31;     // load col
  const int lc = t >> 5;     // load chan base (0..7)
  const int qi = t & 31;     // QK: score row
  const int jg = t >> 5;     // QK: col group (4 cols)
  const int cg = t >> 3;     // PV: chan group (8 chans)
  const int ig = t & 7;      // PV: i group (4 cols)

  #pragma unroll 4
  for (int p = 0; p < 32; ++p)
    Qs[lc + p * 8][li] = qb[(size_t)(lc + p * 8) * NPIX + i0 + li] * 0.0625f;
  if (t < 32) { mrow[t] = -3.0e38f; lrow[t] = 0.f; }

  float O[8][4] = {};
  __syncthreads();

  for (int j0 = 0; j0 < NPIX; j0 += 32) {
    // K tile
    #pragma unroll 4
    for (int p = 0; p < 32; ++p)
      KV[lc + p * 8][li] = kb[(size_t)(lc + p * 8) * NPIX + j0 + li];
    __syncthreads();
    // S = Q^T K  (each thread: 1 row x 4 cols)
    float s0 = 0.f, s1 = 0.f, s2 = 0.f, s3 = 0.f;
    #pragma unroll 8
    for (int c = 0; c < C_; ++c) {
      const float qv = Qs[c][qi];
      s0 += qv * KV[c][jg * 4 + 0];
      s1 += qv * KV[c][jg * 4 + 1];
      s2 += qv * KV[c][jg * 4 + 2];
      s3 += qv * KV[c][jg * 4 + 3];
    }
    Ps[qi][jg * 4 + 0] = s0; Ps[qi][jg * 4 + 1] = s1;
    Ps[qi][jg * 4 + 2] = s2; Ps[qi][jg * 4 + 3] = s3;
    __syncthreads();
    // V tile load (all threads) overlapped with softmax (threads 0..31)
    #pragma unroll 4
    for (int p = 0; p < 32; ++p)
      KV[lc + p * 8][li] = vb[(size_t)(lc + p * 8) * NPIX + j0 + li];
    if (t < 32) {
      const float m = mrow[t];
      float mx = m;
      #pragma unroll
      for (int j = 0; j < 32; ++j) mx = fmaxf(mx, Ps[t][j]);
      const float sc = __expf(m - mx);
      float l = lrow[t] * sc;
      #pragma unroll
      for (int j = 0; j < 32; ++j) {
        const float pe = __expf(Ps[t][j] - mx);
        Ps[t][j] = pe;
        l += pe;
      }
      mrow[t] = mx; lrow[t] = l; srow[t] = sc;
    }
    __syncthreads();
    // rescale O, then O += V * P^T
    {
      const float sc0 = srow[ig * 4 + 0], sc1 = srow[ig * 4 + 1];
      const float sc2 = srow[ig * 4 + 2], sc3 = srow[ig * 4 + 3];
      #pragma unroll
      for (int cc = 0; cc < 8; ++cc) {
        O[cc][0] *= sc0; O[cc][1] *= sc1; O[cc][2] *= sc2; O[cc][3] *= sc3;
      }
    }
    #pragma unroll 4
    for (int j = 0; j < 32; ++j) {
      const float p0 = Ps[ig * 4 + 0][j], p1 = Ps[ig * 4 + 1][j];
      const float p2 = Ps[ig * 4 + 2][j], p3 = Ps[ig * 4 + 3][j];
      #pragma unroll
      for (int cc = 0; cc < 8; ++cc) {
        const float vv = KV[cg * 8 + cc][j];
        O[cc][0] += vv * p0; O[cc][1] += vv * p1;
        O[cc][2] += vv * p2; O[cc][3] += vv * p3;
      }
    }
    __syncthreads();
  }
  // epilogue: normalize by l and store
  float* ob = out + boff;
  const float r0 = 1.f / lrow[ig * 4 + 0], r1 = 1.f / lrow[ig * 4 + 1];
  const float r2 = 1.f / lrow[ig * 4 + 2], r3 = 1.f / lrow[ig * 4 + 3];
  #pragma unroll
  for (int cc = 0; cc < 8; ++cc) {
    const size_t base = (size_t)(cg * 8 + cc) * NPIX + i0 + ig * 4;
    float4 r;
    r.x = O[cc][0] * r0; r.y = O[cc][1] * r1;
    r.z = O[cc][2] * r2; r.w = O[cc][3] * r3;
    *(float4*)&ob[base] = r;
  }
}

// ---------------- launch ----------------
extern "C" void kernel_launch(void* const* d_in, const int* in_sizes, int n_in,
                              void* d_out, int out_size, void* d_ws, size_t ws_size,
                              hipStream_t stream) {
  (void)in_sizes; (void)n_in; (void)out_size; (void)ws_size;
  const float* x      = (const float*)d_in[0];
  const float* norm_w = (const float*)d_in[1];
  const float* norm_b = (const float*)d_in[2];
  const float* wq = (const float*)d_in[3];
  const float* bq = (const float*)d_in[4];
  const float* wk = (const float*)d_in[5];
  const float* bk = (const float*)d_in[6];
  const float* wv = (const float*)d_in[7];
  const float* bv = (const float*)d_in[8];
  const float* wp = (const float*)d_in[9];
  const float* bp = (const float*)d_in[10];
  float* out = (float*)d_out;

  // workspace layout (floats): stats[256] (pad 1024) | hn 8M (reused as attout) | q 8M | k 8M | v 8M
  float* ws    = (float*)d_ws;
  float* stats = ws;
  float* hn    = ws + 1024;
  float* qb    = hn + (size_t)8 * 1024 * 1024;
  float* kb    = qb + (size_t)8 * 1024 * 1024;
  float* vb    = kb + (size_t)8 * 1024 * 1024;

  gn_stats_k<<<B_ * G_, 256, 0, stream>>>((const float4*)x, stats);
  gn_apply_k<<<2048, 256, 0, stream>>>((const float4*)x, stats, norm_w, norm_b, (float4*)hn);

  dim3 gg(NPIX / 64, C_ / 64, B_);
  gemm1x1_k<<<gg, 256, 0, stream>>>(wq, bq, hn, nullptr, qb);
  gemm1x1_k<<<gg, 256, 0, stream>>>(wk, bk, hn, nullptr, kb);
  gemm1x1_k<<<gg, 256, 0, stream>>>(wv, bv, hn, nullptr, vb);

  attn_k<<<B_ * (NPIX / 32), 256, 0, stream>>>(qb, kb, vb, hn);

  gemm1x1_k<<<gg, 256, 0, stream>>>(wp, bp, hn, x, out);
}

// Round 2
// 721.603 us; speedup vs baseline: 5.5850x; 5.5850x over previous
//
#include <hip/hip_runtime.h>

// SpatialSelfAttention: GroupNorm(16) -> q,k,v 1x1 conv -> softmax attention -> proj + residual
// B=8, C=256, H=W=64, N=4096. Round 1: bf16 MFMA flash attention.

#define B_ 8
#define C_ 256
#define NPIX 4096
#define G_ 16

typedef short short8v __attribute__((ext_vector_type(8)));
typedef float f32x4 __attribute__((ext_vector_type(4)));
typedef unsigned short ush4 __attribute__((ext_vector_type(4)));

__device__ __forceinline__ unsigned short f2bf(float f) {
  unsigned u = __builtin_bit_cast(unsigned, f);
  u += 0x7fffu + ((u >> 16) & 1u);
  return (unsigned short)(u >> 16);
}
__device__ __forceinline__ float bf2f(unsigned short h) {
  return __builtin_bit_cast(float, ((unsigned)h) << 16);
}

// ---------------- GroupNorm stats: one block per (b,g) ----------------
__global__ __launch_bounds__(256)
void gn_stats_k(const float4* __restrict__ x4, float* __restrict__ stats) {
  const int bg = blockIdx.x;                       // b*16+g
  const float4* xp = x4 + (size_t)bg * (16 * NPIX / 4);   // 16 channels contiguous
  float s = 0.f, ss = 0.f;
  for (int i = threadIdx.x; i < 16 * NPIX / 4; i += 256) {
    float4 v = xp[i];
    s  += v.x + v.y + v.z + v.w;
    ss += v.x * v.x + v.y * v.y + v.z * v.z + v.w * v.w;
  }
  #pragma unroll
  for (int off = 32; off > 0; off >>= 1) {
    s  += __shfl_down(s, off);
    ss += __shfl_down(ss, off);
  }
  __shared__ float sm[4], sm2[4];
  const int lane = threadIdx.x & 63, wid = threadIdx.x >> 6;
  if (lane == 0) { sm[wid] = s; sm2[wid] = ss; }
  __syncthreads();
  if (threadIdx.x == 0) {
    s  = sm[0] + sm[1] + sm[2] + sm[3];
    ss = sm2[0] + sm2[1] + sm2[2] + sm2[3];
    float mean = s * (1.f / 65536.f);
    float var  = ss * (1.f / 65536.f) - mean * mean;
    stats[bg * 2 + 0] = mean;
    stats[bg * 2 + 1] = rsqrtf(var + 1e-6f);
  }
}

// ---------------- apply GroupNorm -> hn ----------------
__global__ __launch_bounds__(256)
void gn_apply_k(const float4* __restrict__ x4, const float* __restrict__ stats,
                const float* __restrict__ gamma, const float* __restrict__ beta,
                float4* __restrict__ hn4) {
  const size_t total4 = (size_t)B_ * C_ * NPIX / 4;
  for (size_t p = (size_t)blockIdx.x * blockDim.x + threadIdx.x; p < total4;
       p += (size_t)gridDim.x * blockDim.x) {
    const size_t flat = p << 2;
    const int c  = (int)((flat >> 12) & (C_ - 1));
    const int bi = (int)(flat >> 20);
    const int sg = (bi * G_ + (c >> 4)) * 2;
    const float mean = stats[sg], rstd = stats[sg + 1];
    const float scl = rstd * gamma[c];
    const float sh  = beta[c] - mean * scl;
    float4 xv = x4[p];
    float4 r;
    r.x = xv.x * scl + sh; r.y = xv.y * scl + sh;
    r.z = xv.z * scl + sh; r.w = xv.w * scl + sh;
    hn4[p] = r;
  }
}

// ---------------- 1x1 conv GEMM ----------------
// MODE 0: f32 natural [o][n] (+resid) -> dstf
// MODE 1: bf16 TRANSPOSED [n][o], (acc+bias)*scale -> dsth   (q, k)
// MODE 2: bf16 natural [o][n] -> dsth                        (v)
template <int MODE>
__global__ __launch_bounds__(256)
void gemm1x1_k(const float* __restrict__ W, const float* __restrict__ bias,
               const float* __restrict__ src, const float* __restrict__ resid,
               float* __restrict__ dstf, unsigned short* __restrict__ dsth,
               float scale) {
  const int b  = blockIdx.z;
  const int n0 = blockIdx.x * 64;
  const int o0 = blockIdx.y * 64;
  __shared__ float sA[16][68];   // sA[c][o]
  __shared__ float sB[16][68];   // sB[c][n]
  const int t  = threadIdx.x;
  const int tx = t & 15, ty = t >> 4;
  const int ca = t & 15, oa = t >> 4;   // A-load coords
  const int nb = t & 63, cb = t >> 6;   // B-load coords
  const float* srcb = src + (size_t)b * C_ * NPIX;
  float acc[4][4] = {};
  for (int c0 = 0; c0 < C_; c0 += 16) {
    #pragma unroll
    for (int p = 0; p < 4; ++p)
      sA[ca][oa + p * 16] = W[(size_t)(o0 + oa + p * 16) * C_ + c0 + ca];
    #pragma unroll
    for (int p = 0; p < 4; ++p)
      sB[cb + p * 4][nb] = srcb[(size_t)(c0 + cb + p * 4) * NPIX + n0 + nb];
    __syncthreads();
    #pragma unroll
    for (int c = 0; c < 16; ++c) {
      const float4 a  = *(const float4*)&sA[c][ty * 4];
      const float4 bb = *(const float4*)&sB[c][tx * 4];
      const float av[4] = {a.x, a.y, a.z, a.w};
      const float bv[4] = {bb.x, bb.y, bb.z, bb.w};
      #pragma unroll
      for (int m = 0; m < 4; ++m)
        #pragma unroll
        for (int n = 0; n < 4; ++n)
          acc[m][n] += av[m] * bv[n];
    }
    __syncthreads();
  }
  if (MODE == 0) {
    float* dstb = dstf + (size_t)b * C_ * NPIX;
    const float* resb = resid + (size_t)b * C_ * NPIX;
    #pragma unroll
    for (int m = 0; m < 4; ++m) {
      const int o = o0 + ty * 4 + m;
      const float bi = bias[o];
      const size_t base = (size_t)o * NPIX + n0 + tx * 4;
      const float4 rv = *(const float4*)&resb[base];
      float4 r;
      r.x = acc[m][0] + bi + rv.x; r.y = acc[m][1] + bi + rv.y;
      r.z = acc[m][2] + bi + rv.z; r.w = acc[m][3] + bi + rv.w;
      *(float4*)&dstb[base] = r;
    }
  } else if (MODE == 1) {
    unsigned short* db = dsth + (size_t)b * NPIX * C_;
    const float bi0 = bias[o0 + ty * 4 + 0], bi1 = bias[o0 + ty * 4 + 1];
    const float bi2 = bias[o0 + ty * 4 + 2], bi3 = bias[o0 + ty * 4 + 3];
    #pragma unroll
    for (int nn = 0; nn < 4; ++nn) {
      const int n = n0 + tx * 4 + nn;
      ush4 h;
      h[0] = f2bf((acc[0][nn] + bi0) * scale);
      h[1] = f2bf((acc[1][nn] + bi1) * scale);
      h[2] = f2bf((acc[2][nn] + bi2) * scale);
      h[3] = f2bf((acc[3][nn] + bi3) * scale);
      *(ush4*)&db[(size_t)n * C_ + o0 + ty * 4] = h;
    }
  } else {
    unsigned short* db = dsth + (size_t)b * C_ * NPIX;
    #pragma unroll
    for (int m = 0; m < 4; ++m) {
      const int o = o0 + ty * 4 + m;
      const float bi = bias[o];
      ush4 h;
      h[0] = f2bf(acc[m][0] + bi); h[1] = f2bf(acc[m][1] + bi);
      h[2] = f2bf(acc[m][2] + bi); h[3] = f2bf(acc[m][3] + bi);
      *(ush4*)&db[(size_t)o * NPIX + n0 + tx * 4] = h;
    }
  }
}

// ---------------- bf16 MFMA flash attention ----------------
// qt, kt: [b][n][c] bf16 (q pre-scaled by 1/16); vb: [b][c][n] bf16.
// Block: 256 thr = 4 waves, BI=64 queries, BJ=64 keys/iter, online softmax.
// Wave w: QK rows i in [16w,16w+16); PV channel slice c in [64w, 64w+64).
__global__ __launch_bounds__(256, 2)
void attn_k(const unsigned short* __restrict__ qt,
            const unsigned short* __restrict__ kt,
            const unsigned short* __restrict__ vb,
            float* __restrict__ out) {
  __shared__ __align__(16) unsigned char smem[74240];
  unsigned short* Kls = (unsigned short*)smem;            // 32 KB [j][c] swz
  unsigned short* Vls = (unsigned short*)(smem + 32768);  // 32 KB [c][j] swz
  unsigned short* Pls = (unsigned short*)(smem + 65536);  // 8 KB  [i][j] swz
  float* srow = (float*)(smem + 73728);                   // 64 f32
  float* lrow = (float*)(smem + 73984);                   // 64 f32
  float* Obuf = (float*)smem;                             // epilogue bounce (64 KB)

  const int t  = threadIdx.x;
  const int w  = t >> 6;
  const int l  = t & 63;
  const int g2 = l >> 4;
  const int lx = l & 15;

  const int bid = blockIdx.x;
  const int b   = bid & 7;          // batch pinned to XCD
  const int i0  = (bid >> 3) * 64;

  // Q fragments resident in registers: lane row = i0 + 16w + lx
  const unsigned short* qrow = qt + ((size_t)b * NPIX + i0 + 16 * w + lx) * C_;
  short8v qf[8];
  #pragma unroll
  for (int ch = 0; ch < 8; ++ch)
    qf[ch] = *(const short8v*)(qrow + 32 * ch + 8 * g2);

  f32x4 o[4][4];
  #pragma unroll
  for (int a = 0; a < 4; ++a)
    #pragma unroll
    for (int bb = 0; bb < 4; ++bb) {
      o[a][bb][0] = 0.f; o[a][bb][1] = 0.f; o[a][bb][2] = 0.f; o[a][bb][3] = 0.f;
    }

  float m_r[4] = {-3.0e38f, -3.0e38f, -3.0e38f, -3.0e38f};
  float l_r[4] = {0.f, 0.f, 0.f, 0.f};

  const unsigned short* ktb_base = kt + (size_t)b * NPIX * C_;
  const unsigned short* vbb      = vb + (size_t)b * C_ * NPIX;

  for (int j0 = 0; j0 < NPIX; j0 += 64) {
    // ---- issue staging loads into regs (overlaps tail of prev compute) ----
    const unsigned short* ktb = ktb_base + (size_t)j0 * C_;
    short8v kreg[8], vreg[8];
    #pragma unroll
    for (int u = 0; u < 8; ++u)
      kreg[u] = *(const short8v*)(ktb + (size_t)(t + 256 * u) * 8);
    #pragma unroll
    for (int u = 0; u < 8; ++u) {
      const int idx = t + 256 * u;
      vreg[u] = *(const short8v*)(vbb + (size_t)(idx >> 3) * NPIX + j0 + (idx & 7) * 8);
    }
    __syncthreads();   // prior iter's LDS reads complete
    #pragma unroll
    for (int u = 0; u < 8; ++u) {
      const int cidx = t + 256 * u;
      const int j = cidx >> 5, cq = cidx & 31;
      *(short8v*)((unsigned char*)Kls + ((j * 512 + cq * 16) ^ ((j & 7) << 4))) = kreg[u];
    }
    #pragma unroll
    for (int u = 0; u < 8; ++u) {
      const int idx = t + 256 * u;
      const int c = idx >> 3, cq = idx & 7;
      *(short8v*)((unsigned char*)Vls + ((c * 128 + cq * 16) ^ ((c & 7) << 4))) = vreg[u];
    }
    __syncthreads();   // staging visible

    // ---- S = Q^T K (wave rows 16w..16w+16, all 64 j) ----
    f32x4 sacc[4];
    #pragma unroll
    for (int jb = 0; jb < 4; ++jb) {
      sacc[jb][0] = 0.f; sacc[jb][1] = 0.f; sacc[jb][2] = 0.f; sacc[jb][3] = 0.f;
    }
    #pragma unroll
    for (int ch = 0; ch < 8; ++ch) {
      #pragma unroll
      for (int jb = 0; jb < 4; ++jb) {
        const int j = 16 * jb + lx;
        const short8v kf = *(const short8v*)((const unsigned char*)Kls +
            ((j * 512 + 64 * ch + 16 * g2) ^ ((lx & 7) << 4)));
        sacc[jb] = __builtin_amdgcn_mfma_f32_16x16x32_bf16(qf[ch], kf, sacc[jb], 0, 0, 0);
      }
    }

    // ---- online softmax; rows i = 16w + 4g2 + r live across 16-lane group ----
    float sc[4];
    unsigned short pb[4][4];
    #pragma unroll
    for (int r = 0; r < 4; ++r) {
      float mt = fmaxf(fmaxf(sacc[0][r], sacc[1][r]), fmaxf(sacc[2][r], sacc[3][r]));
      #pragma unroll
      for (int msk = 1; msk < 16; msk <<= 1)
        mt = fmaxf(mt, __shfl_xor(mt, msk, 16));
      const float mnew = fmaxf(m_r[r], mt);
      sc[r] = __expf(m_r[r] - mnew);
      m_r[r] = mnew;
      float rs = 0.f;
      #pragma unroll
      for (int jb = 0; jb < 4; ++jb) {
        const float pe = __expf(sacc[jb][r] - mnew);
        const unsigned short h = f2bf(pe);
        pb[jb][r] = h;
        rs += bf2f(h);           // denominator from rounded P for consistency
      }
      #pragma unroll
      for (int msk = 1; msk < 16; msk <<= 1)
        rs += __shfl_xor(rs, msk, 16);
      l_r[r] = l_r[r] * sc[r] + rs;
    }
    #pragma unroll
    for (int jb = 0; jb < 4; ++jb)
      #pragma unroll
      for (int r = 0; r < 4; ++r) {
        const int i = 16 * w + 4 * g2 + r;
        const int j = 16 * jb + lx;
        *(unsigned short*)((unsigned char*)Pls + ((i * 128 + j * 2) ^ ((i & 7) << 4))) = pb[jb][r];
      }
    if (lx == 0) {
      #pragma unroll
      for (int r = 0; r < 4; ++r) srow[16 * w + 4 * g2 + r] = sc[r];
    }
    __syncthreads();   // P + scales ready; all QK reads of Kls done

    // ---- rescale O, then O += V * P^T (wave channels 64w..64w+64, all i) ----
    float sf[4];
    #pragma unroll
    for (int ib = 0; ib < 4; ++ib) sf[ib] = srow[16 * ib + lx];
    #pragma unroll
    for (int cb = 0; cb < 4; ++cb)
      #pragma unroll
      for (int ib = 0; ib < 4; ++ib) {
        o[cb][ib][0] *= sf[ib]; o[cb][ib][1] *= sf[ib];
        o[cb][ib][2] *= sf[ib]; o[cb][ib][3] *= sf[ib];
      }
    #pragma unroll
    for (int ch = 0; ch < 2; ++ch) {
      short8v pf[4], vf[4];
      #pragma unroll
      for (int ib = 0; ib < 4; ++ib) {
        const int i = 16 * ib + lx;
        pf[ib] = *(const short8v*)((const unsigned char*)Pls +
            ((i * 128 + 64 * ch + 16 * g2) ^ ((lx & 7) << 4)));
      }
      #pragma unroll
      for (int cb = 0; cb < 4; ++cb) {
        const int c = 64 * w + 16 * cb + lx;
        vf[cb] = *(const short8v*)((const unsigned char*)Vls +
            ((c * 128 + 64 * ch + 16 * g2) ^ ((lx & 7) << 4)));
      }
      #pragma unroll
      for (int cb = 0; cb < 4; ++cb)
        #pragma unroll
        for (int ib = 0; ib < 4; ++ib)
          o[cb][ib] = __builtin_amdgcn_mfma_f32_16x16x32_bf16(vf[cb], pf[ib], o[cb][ib], 0, 0, 0);
    }
  }

  // ---- epilogue: normalize, LDS transpose bounce, coalesced store ----
  if (lx == 0) {
    #pragma unroll
    for (int r = 0; r < 4; ++r) lrow[16 * w + 4 * g2 + r] = l_r[r];
  }
  __syncthreads();
  float rinv[4];
  #pragma unroll
  for (int ib = 0; ib < 4; ++ib) rinv[ib] = 1.0f / lrow[16 * ib + lx];
  #pragma unroll
  for (int cb = 0; cb < 4; ++cb)
    #pragma unroll
    for (int ib = 0; ib < 4; ++ib)
      #pragma unroll
      for (int r = 0; r < 4; ++r)
        Obuf[(64 * w + 16 * cb + 4 * g2 + r) * 64 + 16 * ib + lx] = o[cb][ib][r] * rinv[ib];
  __syncthreads();
  float* ob = out + (size_t)b * C_ * NPIX + i0;
  #pragma unroll 4
  for (int pass = 0; pass < 16; ++pass) {
    const int c  = (t >> 4) + 16 * pass;
    const int sl = t & 15;
    *(float4*)&ob[(size_t)c * NPIX + sl * 4] = *(const float4*)&Obuf[c * 64 + sl * 4];
  }
}

// ---------------- launch ----------------
extern "C" void kernel_launch(void* const* d_in, const int* in_sizes, int n_in,
                              void* d_out, int out_size, void* d_ws, size_t ws_size,
                              hipStream_t stream) {
  (void)in_sizes; (void)n_in; (void)out_size; (void)ws_size;
  const float* x      = (const float*)d_in[0];
  const float* norm_w = (const float*)d_in[1];
  const float* norm_b = (const float*)d_in[2];
  const float* wq = (const float*)d_in[3];
  const float* bq = (const float*)d_in[4];
  const float* wk = (const float*)d_in[5];
  const float* bk = (const float*)d_in[6];
  const float* wv = (const float*)d_in[7];
  const float* bv = (const float*)d_in[8];
  const float* wp = (const float*)d_in[9];
  const float* bp = (const float*)d_in[10];
  float* out = (float*)d_out;

  // ws layout: stats[1024 f32] | hn/attout [8M f32] | qt | kt | vb (8M ushort each)
  float* ws    = (float*)d_ws;
  float* stats = ws;
  float* hn    = ws + 1024;
  unsigned short* qtb = (unsigned short*)(hn + (size_t)8 * 1024 * 1024);
  unsigned short* ktb = qtb + (size_t)8 * 1024 * 1024;
  unsigned short* vbb = ktb + (size_t)8 * 1024 * 1024;

  gn_stats_k<<<B_ * G_, 256, 0, stream>>>((const float4*)x, stats);
  gn_apply_k<<<2048, 256, 0, stream>>>((const float4*)x, stats, norm_w, norm_b, (float4*)hn);

  dim3 gg(NPIX / 64, C_ / 64, B_);
  gemm1x1_k<1><<<gg, 256, 0, stream>>>(wq, bq, hn, nullptr, nullptr, qtb, 0.0625f);
  gemm1x1_k<1><<<gg, 256, 0, stream>>>(wk, bk, hn, nullptr, nullptr, ktb, 1.0f);
  gemm1x1_k<2><<<gg, 256, 0, stream>>>(wv, bv, hn, nullptr, nullptr, vbb, 1.0f);

  attn_k<<<B_ * (NPIX / 64), 256, 0, stream>>>(qtb, ktb, vbb, hn);

  gemm1x1_k<0><<<gg, 256, 0, stream>>>(wp, bp, hn, x, out, nullptr, 1.0f);
}

// Round 4
// 392.702 us; speedup vs baseline: 10.2627x; 1.8375x over previous
//
#include <hip/hip_runtime.h>

// SpatialSelfAttention: GroupNorm(16) -> q,k,v 1x1 conv -> softmax attention -> proj + residual
// B=8, C=256, H=W=64, N=4096.
// Round 3 = Round 2 resubmission (infra failure last round; kernel never ran).
// Full bf16-MFMA pipeline. Swapped-QK^T flash attention (P in registers via
// cvt_pk+permlane32_swap), global_load_lds double-buffered K/V with pre-swizzled sources,
// GN fused into QKV GEMM staging, MFMA GEMMs for qkv+proj.

#define B_ 8
#define C_ 256
#define NPIX 4096

typedef short short8v __attribute__((ext_vector_type(8)));
typedef unsigned short ush4 __attribute__((ext_vector_type(4)));
typedef float f32x16 __attribute__((ext_vector_type(16)));

__device__ __forceinline__ unsigned short f2bf(float f) {
  unsigned u = __builtin_bit_cast(unsigned, f);
  u += 0x7fffu + ((u >> 16) & 1u);
  return (unsigned short)(u >> 16);
}

__device__ __forceinline__ void gload_lds16(const void* g, void* l) {
  __builtin_amdgcn_global_load_lds((const __attribute__((address_space(1))) void*)g,
                                   (__attribute__((address_space(3))) void*)l, 16, 0, 0);
}

// ---------------- GroupNorm partial stats: 8 blocks per (b,g) ----------------
__global__ __launch_bounds__(256)
void gn_part(const float4* __restrict__ x4, float* __restrict__ part) {
  const int bg = blockIdx.x >> 3;
  const int sl = blockIdx.x & 7;
  const float4* xp = x4 + (size_t)bg * (16 * NPIX / 4) + sl * 128;
  float s = 0.f, ss = 0.f;
  #pragma unroll
  for (int u = 0; u < 8; ++u) {
    const int idx = u * 256 + threadIdx.x;       // 2048 float4 = 16 c x 128 quads
    float4 v = xp[(size_t)(idx >> 7) * (NPIX / 4) + (idx & 127)];
    s  += v.x + v.y + v.z + v.w;
    ss += v.x * v.x + v.y * v.y + v.z * v.z + v.w * v.w;
  }
  #pragma unroll
  for (int off = 32; off; off >>= 1) { s += __shfl_down(s, off); ss += __shfl_down(ss, off); }
  __shared__ float sm1[4], sm2[4];
  const int w = threadIdx.x >> 6, l = threadIdx.x & 63;
  if (l == 0) { sm1[w] = s; sm2[w] = ss; }
  __syncthreads();
  if (threadIdx.x == 0) {
    part[blockIdx.x * 2]     = sm1[0] + sm1[1] + sm1[2] + sm1[3];
    part[blockIdx.x * 2 + 1] = sm2[0] + sm2[1] + sm2[2] + sm2[3];
  }
}

__global__ __launch_bounds__(128)
void gn_fin(const float* __restrict__ part, float* __restrict__ stats) {
  const int t = threadIdx.x;   // 128 = B*G
  float s = 0.f, ss = 0.f;
  #pragma unroll
  for (int p = 0; p < 8; ++p) { s += part[(t * 8 + p) * 2]; ss += part[(t * 8 + p) * 2 + 1]; }
  const float mean = s * (1.f / 65536.f);
  const float var  = ss * (1.f / 65536.f) - mean * mean;
  stats[t * 2]     = mean;
  stats[t * 2 + 1] = rsqrtf(var + 1e-6f);
}

// ---------------- MFMA GEMM (1x1 conv), GN fused into staging ----------------
// MODE 0: D[n][o] = hn[n][.]*W[o][.]  -> bf16 transposed out (q: o<256 scaled 1/16 -> dq; k -> dk)
// MODE 1: D[o][n] -> bf16 natural out (v -> dq)
// MODE 2: D[o][n] + bias + x residual -> f32 out, input = aT bf16 (proj)
template <int MODE>
__global__ __launch_bounds__(256, 2)
void gemm_k(const float* __restrict__ Wa, const float* __restrict__ ba,
            const float* __restrict__ Wb, const float* __restrict__ bb,
            const float* __restrict__ x, const float* __restrict__ stats,
            const float* __restrict__ gamma, const float* __restrict__ beta,
            const unsigned short* __restrict__ aT,
            unsigned short* __restrict__ dq, unsigned short* __restrict__ dk,
            float* __restrict__ dout) {
  extern __shared__ __align__(16) unsigned char sm[];
  unsigned char* sX = sm;            // [2][128n][64c] bf16, row 128B, xor ((n&7)<<4)
  unsigned char* sW = sm + 32768;    // [2][128o][64c] bf16
  float* sscl = (float*)(sm + 65536);
  float* ssh  = sscl + 256;

  const int t = threadIdx.x;
  const int w = t >> 6, l = t & 63, hi = l >> 5, ln = l & 31;
  const int b  = blockIdx.z;
  const int n0 = blockIdx.x * 128;
  const int o0 = blockIdx.y * 128;

  const float* Wsel = (MODE == 0 && o0 >= 256) ? Wb : Wa;
  const float* bsel = (MODE == 0 && o0 >= 256) ? bb : ba;
  const int orow0 = o0 & 255;

  if (MODE < 2) {
    const int c = t;
    const float mean = stats[(b * 16 + (c >> 4)) * 2];
    const float rstd = stats[(b * 16 + (c >> 4)) * 2 + 1];
    const float sl = rstd * gamma[c];
    sscl[c] = sl; ssh[c] = beta[c] - mean * sl;
  }
  __syncthreads();

  const float* xb = x + (size_t)b * C_ * NPIX;
  const unsigned short* aTb = aT + (size_t)b * NPIX * C_;

  auto stage = [&](int s) {
    const int c0 = s * 64;
    unsigned char* Xb_ = sX + (s & 1) * 16384;
    unsigned char* Wb_ = sW + (s & 1) * 16384;
    // W tile
    #pragma unroll
    for (int i = 0; i < 8; ++i) {
      const int idx = i * 256 + t;
      const int o = idx >> 4;
      const int cq = (idx & 15) * 4;
      float4 v = *(const float4*)&Wsel[(size_t)(orow0 + o) * C_ + c0 + cq];
      ush4 h; h[0] = f2bf(v.x); h[1] = f2bf(v.y); h[2] = f2bf(v.z); h[3] = f2bf(v.w);
      *(ush4*)(Wb_ + ((o * 128 + cq * 2) ^ ((o & 7) << 4))) = h;
    }
    // X tile
    if (MODE < 2) {
      const int co = t & 7, q = t >> 3;
      float vv[8][4];
      #pragma unroll
      for (int i = 0; i < 8; ++i) {
        const int c = c0 + 8 * co + i;
        float4 v = *(const float4*)&xb[(size_t)c * NPIX + n0 + 4 * q];
        const float slc = sscl[c], shc = ssh[c];
        vv[i][0] = v.x * slc + shc; vv[i][1] = v.y * slc + shc;
        vv[i][2] = v.z * slc + shc; vv[i][3] = v.w * slc + shc;
      }
      #pragma unroll
      for (int nn = 0; nn < 4; ++nn) {
        short8v h;
        #pragma unroll
        for (int j = 0; j < 8; ++j) h[j] = (short)f2bf(vv[j][nn]);
        const int n = 4 * q + nn;
        *(short8v*)(Xb_ + ((n * 128 + 16 * co) ^ ((n & 7) << 4))) = h;
      }
    } else {
      const int cs = t & 7, nb = t >> 3;
      #pragma unroll
      for (int r = 0; r < 4; ++r) {
        const int n = nb + 32 * r;
        short8v v = *(const short8v*)&aTb[(size_t)(n0 + n) * C_ + c0 + 8 * cs];
        *(short8v*)(Xb_ + ((n * 128 + 16 * cs) ^ ((n & 7) << 4))) = v;
      }
    }
  };

  f32x16 acc[2][2];
  #pragma unroll
  for (int i = 0; i < 2; ++i)
    #pragma unroll
    for (int j = 0; j < 2; ++j)
      #pragma unroll
      for (int r = 0; r < 16; ++r) acc[i][j][r] = 0.f;

  stage(0);
  __syncthreads();
  for (int s = 0; s < 4; ++s) {
    if (s < 3) stage(s + 1);
    const unsigned char* Xb_ = sX + (s & 1) * 16384;
    const unsigned char* Wb_ = sW + (s & 1) * 16384;
    #pragma unroll
    for (int ks = 0; ks < 4; ++ks) {
      short8v xa[2], wf[2];
      #pragma unroll
      for (int mt = 0; mt < 2; ++mt) {
        const int n = 64 * (w >> 1) + 32 * mt + ln;
        xa[mt] = *(const short8v*)(Xb_ + ((n * 128 + 32 * ks + 16 * hi) ^ ((n & 7) << 4)));
        const int o = 64 * (w & 1) + 32 * mt + ln;
        wf[mt] = *(const short8v*)(Wb_ + ((o * 128 + 32 * ks + 16 * hi) ^ ((o & 7) << 4)));
      }
      #pragma unroll
      for (int mt = 0; mt < 2; ++mt)
        #pragma unroll
        for (int nt = 0; nt < 2; ++nt)
          acc[mt][nt] = (MODE == 0)
            ? __builtin_amdgcn_mfma_f32_32x32x16_bf16(xa[mt], wf[nt], acc[mt][nt], 0, 0, 0)
            : __builtin_amdgcn_mfma_f32_32x32x16_bf16(wf[mt], xa[nt], acc[mt][nt], 0, 0, 0);
    }
    __syncthreads();
  }

  if (MODE == 0) {
    unsigned short* dst = (o0 < 256) ? dq : dk;
    const float scv = (o0 < 256) ? 0.0625f : 1.0f;
    #pragma unroll
    for (int nt = 0; nt < 2; ++nt) {
      const int o = o0 + 64 * (w & 1) + 32 * nt + ln;
      const float bi = bsel[o & 255];
      #pragma unroll
      for (int mt = 0; mt < 2; ++mt)
        #pragma unroll
        for (int r = 0; r < 16; ++r) {
          const int n = n0 + 64 * (w >> 1) + 32 * mt + (r & 3) + 8 * (r >> 2) + 4 * hi;
          dst[((size_t)b * NPIX + n) * C_ + (o & 255)] = f2bf((acc[mt][nt][r] + bi) * scv);
        }
    }
  } else if (MODE == 1) {
    #pragma unroll
    for (int nt = 0; nt < 2; ++nt) {
      const int n = n0 + 64 * (w >> 1) + 32 * nt + ln;
      #pragma unroll
      for (int mt = 0; mt < 2; ++mt)
        #pragma unroll
        for (int r = 0; r < 16; ++r) {
          const int o = o0 + 64 * (w & 1) + 32 * mt + (r & 3) + 8 * (r >> 2) + 4 * hi;
          dq[((size_t)b * C_ + o) * NPIX + n] = f2bf(acc[mt][nt][r] + ba[o]);
        }
    }
  } else {
    #pragma unroll
    for (int nt = 0; nt < 2; ++nt) {
      const int n = n0 + 64 * (w >> 1) + 32 * nt + ln;
      #pragma unroll
      for (int mt = 0; mt < 2; ++mt)
        #pragma unroll
        for (int r = 0; r < 16; ++r) {
          const int o = o0 + 64 * (w & 1) + 32 * mt + (r & 3) + 8 * (r >> 2) + 4 * hi;
          const size_t ad = ((size_t)b * C_ + o) * NPIX + n;
          dout[ad] = acc[mt][nt][r] + ba[o] + x[ad];
        }
    }
  }
}

// ---------------- bf16 MFMA flash attention, swapped QK^T ----------------
// qt, kt: [b][n][c] bf16 (q pre-scaled 1/16); vb: [b][c][n] bf16; out aT: [b][n][c] bf16.
// 256 blocks (1/CU), 4 waves x 32 queries = BI 128; BJ=64/iter; K/V double-buffered
// via global_load_lds with pre-swizzled global sources; P stays in registers
// (cvt_pk_bf16 + permlane32_swap); O: 256c x 32i in 128 VGPRs per lane.
__global__ __launch_bounds__(256, 1)
void attn_k(const unsigned short* __restrict__ qt,
            const unsigned short* __restrict__ kt,
            const unsigned short* __restrict__ vb,
            unsigned short* __restrict__ aT) {
  extern __shared__ __align__(16) unsigned char smem[];
  // [0,64K): K dbuf 2x32KB  [j 64][c 256] xor ((j&7)<<4)
  // [64K,128K): V dbuf 2x32KB [c 256][j 64] xor ((c&7)<<4)
  const int t = threadIdx.x;
  const int w = t >> 6, l = t & 63, hi = l >> 5, ln = l & 31;
  const int bid = blockIdx.x;
  const int b = bid & 7;                 // batch pinned to XCD
  const int i0 = (bid >> 3) * 128;

  const size_t nc = (size_t)NPIX * C_;
  const unsigned short* qb  = qt + (size_t)b * nc;
  const unsigned char*  kbb = (const unsigned char*)(kt + (size_t)b * nc);
  const unsigned char*  vbb = (const unsigned char*)(vb + (size_t)b * nc);

  // Q fragments resident: rows i = i0 + 32w + ln
  const unsigned short* qrow = qb + (size_t)(i0 + 32 * w + ln) * C_ + 8 * hi;
  short8v qf[16];
  #pragma unroll
  for (int cs = 0; cs < 16; ++cs) qf[cs] = *(const short8v*)(qrow + 16 * cs);

  f32x16 Ot[8];
  #pragma unroll
  for (int ct = 0; ct < 8; ++ct)
    #pragma unroll
    for (int r = 0; r < 16; ++r) Ot[ct][r] = 0.f;
  float m_r = -3.0e38f, l_r = 0.f;

  auto stage = [&](int buf, int j0) {
    unsigned char* Kd = smem + buf * 32768;
    unsigned char* Vd = smem + 65536 + buf * 32768;
    #pragma unroll
    for (int u = 0; u < 8; ++u) {
      const int p = w * 8192 + u * 1024 + l * 16;
      const int j = p >> 9;
      const int inner = (p & 511) ^ ((j & 7) << 4);
      gload_lds16(kbb + (size_t)(j0 + j) * 512 + inner, Kd + w * 8192 + u * 1024);
    }
    #pragma unroll
    for (int u = 0; u < 8; ++u) {
      const int p = w * 8192 + u * 1024 + l * 16;
      const int c = p >> 7;
      const int inner = (p & 127) ^ ((c & 7) << 4);
      gload_lds16(vbb + (size_t)c * 8192 + j0 * 2 + inner, Vd + w * 8192 + u * 1024);
    }
  };

  stage(0, 0);
  __syncthreads();

  for (int it = 0; it < 64; ++it) {
    const int cur = it & 1;
    if (it < 63) stage(cur ^ 1, (it + 1) * 64);

    // ---- S^T[j 64][i 32] = mfma(K, Q) ----
    const unsigned char* Kb = smem + cur * 32768;
    f32x16 st0, st1;
    #pragma unroll
    for (int r = 0; r < 16; ++r) { st0[r] = 0.f; st1[r] = 0.f; }
    #pragma unroll
    for (int cs = 0; cs < 16; ++cs) {
      const int cb = 32 * cs + 16 * hi;
      short8v kf0 = *(const short8v*)(Kb + ((ln * 512 + cb) ^ ((ln & 7) << 4)));
      st0 = __builtin_amdgcn_mfma_f32_32x32x16_bf16(kf0, qf[cs], st0, 0, 0, 0);
      short8v kf1 = *(const short8v*)(Kb + (((32 + ln) * 512 + cb) ^ ((ln & 7) << 4)));
      st1 = __builtin_amdgcn_mfma_f32_32x32x16_bf16(kf1, qf[cs], st1, 0, 0, 0);
    }

    // ---- online softmax, fully lane-local (i = ln, halves combined via shfl 32) ----
    float mt = st0[0];
    #pragma unroll
    for (int r = 1; r < 16; ++r) mt = fmaxf(mt, st0[r]);
    #pragma unroll
    for (int r = 0; r < 16; ++r) mt = fmaxf(mt, st1[r]);
    mt = fmaxf(mt, __shfl_xor(mt, 32));
    const float mnew = fmaxf(m_r, mt);
    const float sc = __expf(m_r - mnew);
    m_r = mnew;
    float rs = 0.f;
    #pragma unroll
    for (int r = 0; r < 16; ++r) { st0[r] = __expf(st0[r] - mnew); rs += st0[r]; }
    #pragma unroll
    for (int r = 0; r < 16; ++r) { st1[r] = __expf(st1[r] - mnew); rs += st1[r]; }
    rs += __shfl_xor(rs, 32);
    l_r = l_r * sc + rs;
    #pragma unroll
    for (int ct = 0; ct < 8; ++ct) Ot[ct] *= sc;

    // ---- P -> B-frags in-register: cvt_pk pairs + permlane32_swap ----
    short8v pf[4];
    #pragma unroll
    for (int g = 0; g < 4; ++g) {
      f32x16 sv = (g < 2) ? st0 : st1;
      const int rb = (g & 1) * 8;
      unsigned pk01, pk23, pk45, pk67;
      asm("v_cvt_pk_bf16_f32 %0, %1, %2" : "=v"(pk01) : "v"(sv[rb + 0]), "v"(sv[rb + 1]));
      asm("v_cvt_pk_bf16_f32 %0, %1, %2" : "=v"(pk23) : "v"(sv[rb + 2]), "v"(sv[rb + 3]));
      asm("v_cvt_pk_bf16_f32 %0, %1, %2" : "=v"(pk45) : "v"(sv[rb + 4]), "v"(sv[rb + 5]));
      asm("v_cvt_pk_bf16_f32 %0, %1, %2" : "=v"(pk67) : "v"(sv[rb + 6]), "v"(sv[rb + 7]));
      asm volatile("v_permlane32_swap_b32 %0, %1" : "+v"(pk01), "+v"(pk45));
      asm volatile("v_permlane32_swap_b32 %0, %1" : "+v"(pk23), "+v"(pk67));
      int4 fi = {(int)pk01, (int)pk23, (int)pk45, (int)pk67};
      pf[g] = __builtin_bit_cast(short8v, fi);
    }

    // ---- O[c 256][i 32] += V * P ----
    const unsigned char* Vbuf = smem + 65536 + cur * 32768;
    #pragma unroll
    for (int ks = 0; ks < 4; ++ks) {
      #pragma unroll
      for (int ct = 0; ct < 8; ++ct) {
        const int c = 32 * ct + ln;
        short8v vf = *(const short8v*)(Vbuf + ((c * 128 + 32 * ks + 16 * hi) ^ ((c & 7) << 4)));
        Ot[ct] = __builtin_amdgcn_mfma_f32_32x32x16_bf16(vf, pf[ks], Ot[ct], 0, 0, 0);
      }
    }
    __syncthreads();
  }

  // ---- epilogue: normalize, pack O^T rows in-register, LDS bounce, coalesced bf16 store ----
  const float rinv = 1.0f / l_r;
  const int iloc = 32 * w + ln;
  #pragma unroll
  for (int ct = 0; ct < 8; ++ct) {
    #pragma unroll
    for (int h = 0; h < 2; ++h) {
      const int rb = h * 8;
      unsigned pk01, pk23, pk45, pk67;
      float q0 = Ot[ct][rb + 0] * rinv, q1 = Ot[ct][rb + 1] * rinv;
      float q2 = Ot[ct][rb + 2] * rinv, q3 = Ot[ct][rb + 3] * rinv;
      float q4 = Ot[ct][rb + 4] * rinv, q5 = Ot[ct][rb + 5] * rinv;
      float q6 = Ot[ct][rb + 6] * rinv, q7 = Ot[ct][rb + 7] * rinv;
      asm("v_cvt_pk_bf16_f32 %0, %1, %2" : "=v"(pk01) : "v"(q0), "v"(q1));
      asm("v_cvt_pk_bf16_f32 %0, %1, %2" : "=v"(pk23) : "v"(q2), "v"(q3));
      asm("v_cvt_pk_bf16_f32 %0, %1, %2" : "=v"(pk45) : "v"(q4), "v"(q5));
      asm("v_cvt_pk_bf16_f32 %0, %1, %2" : "=v"(pk67) : "v"(q6), "v"(q7));
      asm volatile("v_permlane32_swap_b32 %0, %1" : "+v"(pk01), "+v"(pk45));
      asm volatile("v_permlane32_swap_b32 %0, %1" : "+v"(pk23), "+v"(pk67));
      int4 fi = {(int)pk01, (int)pk23, (int)pk45, (int)pk67};
      const int byte = (iloc * 512 + 64 * ct + 32 * h + 16 * hi) ^ ((iloc & 7) << 4);
      *(short8v*)(smem + byte) = __builtin_bit_cast(short8v, fi);
    }
  }
  __syncthreads();
  unsigned char* aTb = (unsigned char*)(aT + ((size_t)b * NPIX + i0) * C_);
  #pragma unroll
  for (int p = 0; p < 16; ++p) {
    const int idx = p * 256 + t;
    const int il = idx >> 5, ch = idx & 31;
    const int byte = (il * 512 + ch * 16) ^ ((il & 7) << 4);
    *(short8v*)(aTb + il * 512 + ch * 16) = *(const short8v*)(smem + byte);
  }
}

// ---------------- launch ----------------
extern "C" void kernel_launch(void* const* d_in, const int* in_sizes, int n_in,
                              void* d_out, int out_size, void* d_ws, size_t ws_size,
                              hipStream_t stream) {
  (void)in_sizes; (void)n_in; (void)out_size; (void)ws_size;
  const float* x      = (const float*)d_in[0];
  const float* norm_w = (const float*)d_in[1];
  const float* norm_b = (const float*)d_in[2];
  const float* wq = (const float*)d_in[3];
  const float* bq = (const float*)d_in[4];
  const float* wk = (const float*)d_in[5];
  const float* bk = (const float*)d_in[6];
  const float* wv = (const float*)d_in[7];
  const float* bv = (const float*)d_in[8];
  const float* wp = (const float*)d_in[9];
  const float* bp = (const float*)d_in[10];
  float* out = (float*)d_out;

  // ws layout (bytes): part[8KB] | stats[1KB pad to 64KB] | qt 16MB | kt 16MB | vb 16MB | aT 16MB
  unsigned char* ws = (unsigned char*)d_ws;
  float* part  = (float*)ws;
  float* stats = (float*)(ws + 8192);
  unsigned short* qtb = (unsigned short*)(ws + 65536);
  unsigned short* ktb = qtb + (size_t)8 * 1024 * 1024;
  unsigned short* vbb = ktb + (size_t)8 * 1024 * 1024;
  unsigned short* aTb = vbb + (size_t)8 * 1024 * 1024;

  hipFuncSetAttribute((const void*)gemm_k<0>, hipFuncAttributeMaxDynamicSharedMemorySize, 67584);
  hipFuncSetAttribute((const void*)gemm_k<1>, hipFuncAttributeMaxDynamicSharedMemorySize, 67584);
  hipFuncSetAttribute((const void*)gemm_k<2>, hipFuncAttributeMaxDynamicSharedMemorySize, 67584);
  hipFuncSetAttribute((const void*)attn_k,    hipFuncAttributeMaxDynamicSharedMemorySize, 131072);

  gn_part<<<1024, 256, 0, stream>>>((const float4*)x, part);
  gn_fin<<<1, 128, 0, stream>>>(part, stats);

  gemm_k<0><<<dim3(32, 4, B_), 256, 67584, stream>>>(wq, bq, wk, bk, x, stats, norm_w, norm_b,
                                                     nullptr, qtb, ktb, nullptr);
  gemm_k<1><<<dim3(32, 2, B_), 256, 67584, stream>>>(wv, bv, nullptr, nullptr, x, stats, norm_w, norm_b,
                                                     nullptr, vbb, nullptr, nullptr);

  attn_k<<<256, 256, 131072, stream>>>(qtb, ktb, vbb, aTb);

  gemm_k<2><<<dim3(32, 2, B_), 256, 67584, stream>>>(wp, bp, nullptr, nullptr, x, nullptr, nullptr, nullptr,
                                                     aTb, nullptr, nullptr, out);
}

// Round 5
// 345.930 us; speedup vs baseline: 11.6503x; 1.1352x over previous
//
#include <hip/hip_runtime.h>

// SpatialSelfAttention: GroupNorm(16) -> q,k,v 1x1 conv -> softmax attention -> proj + residual
// B=8, C=256, H=W=64, N=4096.
// Round 5: split-j flash attention (2 blocks/CU -> 2 waves/SIMD), conflict-free granule LDS
// layouts, exp2-domain softmax with deferred rescale, merged QKV GEMM with coalesced epilogues.

#define B_ 8
#define C_ 256
#define NPIX 4096

typedef short short8v __attribute__((ext_vector_type(8)));
typedef unsigned short ush4 __attribute__((ext_vector_type(4)));
typedef unsigned short ush8 __attribute__((ext_vector_type(8)));
typedef float f32x16 __attribute__((ext_vector_type(16)));

__device__ __forceinline__ unsigned short f2bf(float f) {
  unsigned u = __builtin_bit_cast(unsigned, f);
  u += 0x7fffu + ((u >> 16) & 1u);
  return (unsigned short)(u >> 16);
}

__device__ __forceinline__ void gload_lds16(const void* g, void* l) {
  __builtin_amdgcn_global_load_lds((const __attribute__((address_space(1))) void*)g,
                                   (__attribute__((address_space(3))) void*)l, 16, 0, 0);
}

// ---------------- GroupNorm partial stats: 8 blocks per (b,g) ----------------
__global__ __launch_bounds__(256)
void gn_part(const float4* __restrict__ x4, float* __restrict__ part) {
  const int bg = blockIdx.x >> 3;
  const int sl = blockIdx.x & 7;
  const float4* xp = x4 + (size_t)bg * (16 * NPIX / 4) + sl * 128;
  float s = 0.f, ss = 0.f;
  #pragma unroll
  for (int u = 0; u < 8; ++u) {
    const int idx = u * 256 + threadIdx.x;
    float4 v = xp[(size_t)(idx >> 7) * (NPIX / 4) + (idx & 127)];
    s  += v.x + v.y + v.z + v.w;
    ss += v.x * v.x + v.y * v.y + v.z * v.z + v.w * v.w;
  }
  #pragma unroll
  for (int off = 32; off; off >>= 1) { s += __shfl_down(s, off); ss += __shfl_down(ss, off); }
  __shared__ float sm1[4], sm2[4];
  const int w = threadIdx.x >> 6, l = threadIdx.x & 63;
  if (l == 0) { sm1[w] = s; sm2[w] = ss; }
  __syncthreads();
  if (threadIdx.x == 0) {
    part[blockIdx.x * 2]     = sm1[0] + sm1[1] + sm1[2] + sm1[3];
    part[blockIdx.x * 2 + 1] = sm2[0] + sm2[1] + sm2[2] + sm2[3];
  }
}

__global__ __launch_bounds__(128)
void gn_fin(const float* __restrict__ part, float* __restrict__ stats) {
  const int t = threadIdx.x;   // 128 = B*G
  float s = 0.f, ss = 0.f;
  #pragma unroll
  for (int p = 0; p < 8; ++p) { s += part[(t * 8 + p) * 2]; ss += part[(t * 8 + p) * 2 + 1]; }
  const float mean = s * (1.f / 65536.f);
  const float var  = ss * (1.f / 65536.f) - mean * mean;
  stats[t * 2]     = mean;
  stats[t * 2 + 1] = rsqrtf(var + 1e-6f);
}

// ---------------- merged QKV GEMM (1x1 conv), GN fused into staging ----------------
// y=0,1: q -> qt [n][c] bf16 scaled by log2e/16; y=2,3: k -> kt [n][c]; y=4,5: v -> vo [c][n]
__global__ __launch_bounds__(256, 2)
void qkv_k(const float* __restrict__ wq, const float* __restrict__ bq,
           const float* __restrict__ wk, const float* __restrict__ bk,
           const float* __restrict__ wv, const float* __restrict__ bv,
           const float* __restrict__ x, const float* __restrict__ stats,
           const float* __restrict__ gamma, const float* __restrict__ beta,
           unsigned short* __restrict__ qt, unsigned short* __restrict__ kt,
           unsigned short* __restrict__ vo) {
  extern __shared__ __align__(16) unsigned char sm[];
  unsigned char* sX = sm;            // [2][128n][64c] bf16, row 128B, xor ((n&7)<<4)
  unsigned char* sW = sm + 32768;    // [2][128o][64c] bf16
  float* sscl = (float*)(sm + 65536);
  float* ssh  = sscl + 256;

  const int t = threadIdx.x;
  const int w = t >> 6, l = t & 63, hi = l >> 5, ln = l & 31;
  const int b  = blockIdx.z;
  const int n0 = blockIdx.x * 128;
  const int y  = blockIdx.y;
  const bool vmode = (y >= 4);
  const float* W   = (y < 2) ? wq : ((y < 4) ? wk : wv);
  const float* bia = (y < 2) ? bq : ((y < 4) ? bk : bv);
  const int o0 = (y & 1) * 128;

  {
    const int c = t;
    const float mean = stats[(b * 16 + (c >> 4)) * 2];
    const float rstd = stats[(b * 16 + (c >> 4)) * 2 + 1];
    const float sl = rstd * gamma[c];
    sscl[c] = sl; ssh[c] = beta[c] - mean * sl;
  }
  __syncthreads();

  const float* xb = x + (size_t)b * C_ * NPIX;

  auto stage = [&](int s) {
    const int c0 = s * 64;
    unsigned char* Xb_ = sX + (s & 1) * 16384;
    unsigned char* Wb_ = sW + (s & 1) * 16384;
    #pragma unroll
    for (int i = 0; i < 8; ++i) {
      const int idx = i * 256 + t;
      const int o = idx >> 4;
      const int cq = (idx & 15) * 4;
      float4 v = *(const float4*)&W[(size_t)(o0 + o) * C_ + c0 + cq];
      ush4 h; h[0] = f2bf(v.x); h[1] = f2bf(v.y); h[2] = f2bf(v.z); h[3] = f2bf(v.w);
      *(ush4*)(Wb_ + ((o * 128 + cq * 2) ^ ((o & 7) << 4))) = h;
    }
    const int co = t & 7, q = t >> 3;
    float vv[8][4];
    #pragma unroll
    for (int i = 0; i < 8; ++i) {
      const int c = c0 + 8 * co + i;
      float4 v = *(const float4*)&xb[(size_t)c * NPIX + n0 + 4 * q];
      const float slc = sscl[c], shc = ssh[c];
      vv[i][0] = v.x * slc + shc; vv[i][1] = v.y * slc + shc;
      vv[i][2] = v.z * slc + shc; vv[i][3] = v.w * slc + shc;
    }
    #pragma unroll
    for (int nn = 0; nn < 4; ++nn) {
      short8v h;
      #pragma unroll
      for (int j = 0; j < 8; ++j) h[j] = (short)f2bf(vv[j][nn]);
      const int n = 4 * q + nn;
      *(short8v*)(Xb_ + ((n * 128 + 16 * co) ^ ((n & 7) << 4))) = h;
    }
  };

  f32x16 acc[2][2];
  #pragma unroll
  for (int i = 0; i < 2; ++i)
    #pragma unroll
    for (int j = 0; j < 2; ++j)
      #pragma unroll
      for (int r = 0; r < 16; ++r) acc[i][j][r] = 0.f;

  stage(0);
  __syncthreads();
  for (int s = 0; s < 4; ++s) {
    if (s < 3) stage(s + 1);
    const unsigned char* Xb_ = sX + (s & 1) * 16384;
    const unsigned char* Wb_ = sW + (s & 1) * 16384;
    #pragma unroll
    for (int ks = 0; ks < 4; ++ks) {
      short8v xa[2], wf[2];
      #pragma unroll
      for (int mt = 0; mt < 2; ++mt) {
        const int n = 64 * (w >> 1) + 32 * mt + ln;
        xa[mt] = *(const short8v*)(Xb_ + ((n * 128 + 32 * ks + 16 * hi) ^ ((n & 7) << 4)));
        const int o = 64 * (w & 1) + 32 * mt + ln;
        wf[mt] = *(const short8v*)(Wb_ + ((o * 128 + 32 * ks + 16 * hi) ^ ((o & 7) << 4)));
      }
      if (!vmode) {
        #pragma unroll
        for (int mt = 0; mt < 2; ++mt)
          #pragma unroll
          for (int nt = 0; nt < 2; ++nt)
            acc[mt][nt] = __builtin_amdgcn_mfma_f32_32x32x16_bf16(xa[mt], wf[nt], acc[mt][nt], 0, 0, 0);
      } else {
        #pragma unroll
        for (int mt = 0; mt < 2; ++mt)
          #pragma unroll
          for (int nt = 0; nt < 2; ++nt)
            acc[mt][nt] = __builtin_amdgcn_mfma_f32_32x32x16_bf16(wf[mt], xa[nt], acc[mt][nt], 0, 0, 0);
      }
    }
    __syncthreads();
  }

  // ---- LDS-bounce epilogue: tile[R 128][L 128] ushort (32 KB), then 16B stores ----
  unsigned short* tile = (unsigned short*)sm;
  const float qsc = (y < 2) ? (0.0625f * 1.44269504088896340736f) : 1.0f;
  #pragma unroll
  for (int mt = 0; mt < 2; ++mt)
    #pragma unroll
    for (int nt = 0; nt < 2; ++nt)
      #pragma unroll
      for (int r = 0; r < 16; ++r) {
        const int crow = (r & 3) + 8 * (r >> 2) + 4 * hi;
        int R, L; float val;
        if (!vmode) {
          R = 64 * (w >> 1) + 32 * mt + crow;
          L = 64 * (w & 1) + 32 * nt + ln;
          val = (acc[mt][nt][r] + bia[o0 + L]) * qsc;
        } else {
          R = 64 * (w & 1) + 32 * mt + crow;
          L = 64 * (w >> 1) + 32 * nt + ln;
          val = acc[mt][nt][r] + bia[o0 + R];
        }
        tile[R * 128 + L] = f2bf(val);
      }
  __syncthreads();
  if (!vmode) {
    unsigned short* dst = ((y < 2) ? qt : kt) + ((size_t)b * NPIX + n0) * C_ + o0;
    #pragma unroll
    for (int u = 0; u < 8; ++u) {
      const int idx = u * 256 + t;
      const int R = idx >> 4, cb = idx & 15;
      *(ush8*)(dst + (size_t)R * C_ + cb * 8) = *(const ush8*)&tile[R * 128 + cb * 8];
    }
  } else {
    unsigned short* dst = vo + ((size_t)b * C_ + o0) * NPIX + n0;
    #pragma unroll
    for (int u = 0; u < 8; ++u) {
      const int idx = u * 256 + t;
      const int R = idx >> 4, cb = idx & 15;
      *(ush8*)(dst + (size_t)R * NPIX + cb * 8) = *(const ush8*)&tile[R * 128 + cb * 8];
    }
  }
}

// ---------------- split-j bf16 MFMA flash attention ----------------
// qt, kt: [b][n][c] bf16 (q pre-scaled log2e/16); vb: [b][c][n] bf16.
// 512 blocks (2/CU -> 2 waves/SIMD), 4 waves x 32 queries = 128 i/block, each block
// covers j-half of 2048 (64 iters of BJ=32). K/V double-buffered via global_load_lds
// into conflict-free granule layouts. Softmax in exp2 domain, deferred rescale (THR=8).
// Outputs partial O (f32 [half][b][c][i]) + (m,l) for the combine pass.
__global__ __launch_bounds__(256, 2)
void attn_k(const unsigned short* __restrict__ qt,
            const unsigned short* __restrict__ kt,
            const unsigned short* __restrict__ vb,
            float* __restrict__ pO, float* __restrict__ pml) {
  extern __shared__ __align__(16) unsigned char smem[];
  // [0,32K): K dbuf 2x16KB, granule idx = cg*32 + j  (cg in [0,16): 8-chan slice; j in [0,32))
  // [32K,64K): V dbuf 2x16KB, granule idx = g*256 + c (g in [0,4): 8-j slice; c in [0,256))
  const int t = threadIdx.x;
  const int w = t >> 6, l = t & 63, hi = l >> 5, ln = l & 31;
  const int bid = blockIdx.x;
  const int b   = bid & 7;               // batch pinned to XCD
  const int jh  = (bid >> 3) & 1;
  const int i0  = (bid >> 4) * 128;
  const int jbase = jh * 2048;

  const size_t nc = (size_t)NPIX * C_;
  const unsigned short* qb  = qt + (size_t)b * nc;
  const unsigned char*  kbb = (const unsigned char*)(kt + (size_t)b * nc);
  const unsigned char*  vbb = (const unsigned char*)(vb + (size_t)b * nc);

  // Q fragments resident: rows i = i0 + 32w + ln
  const unsigned short* qrow = qb + (size_t)(i0 + 32 * w + ln) * C_ + 8 * hi;
  short8v qf[16];
  #pragma unroll
  for (int cs = 0; cs < 16; ++cs) qf[cs] = *(const short8v*)(qrow + 16 * cs);

  f32x16 Ot[8];
  #pragma unroll
  for (int ct = 0; ct < 8; ++ct)
    #pragma unroll
    for (int r = 0; r < 16; ++r) Ot[ct][r] = 0.f;
  float m_r = -3.0e38f, l_r = 0.f;

  auto stage = [&](int buf, int j0) {
    unsigned char* Kd = smem + buf * 16384;
    unsigned char* Vd = smem + 32768 + buf * 16384;
    #pragma unroll
    for (int u = 0; u < 4; ++u) {
      const int idx = u * 256 + t;
      gload_lds16(kbb + (size_t)(j0 + (idx & 31)) * 512 + (idx >> 5) * 16, Kd + idx * 16);
    }
    #pragma unroll
    for (int u = 0; u < 4; ++u) {
      const int idx = u * 256 + t;
      gload_lds16(vbb + (size_t)(idx & 255) * 8192 + j0 * 2 + (idx >> 8) * 16, Vd + idx * 16);
    }
  };

  stage(0, jbase);
  __syncthreads();

  for (int it = 0; it < 64; ++it) {
    const int cur = it & 1;
    if (it < 63) stage(cur ^ 1, jbase + (it + 1) * 32);

    // ---- S^T[32j][32i] = mfma(K, Q); lane: col i = ln, rows j = (r&3)+8(r>>2)+4hi ----
    const unsigned char* Kb = smem + cur * 16384;
    f32x16 st;
    #pragma unroll
    for (int r = 0; r < 16; ++r) st[r] = 0.f;
    #pragma unroll
    for (int cs = 0; cs < 16; ++cs) {
      const short8v kf = *(const short8v*)(Kb + ((2 * cs + hi) * 32 + ln) * 16);
      st = __builtin_amdgcn_mfma_f32_32x32x16_bf16(kf, qf[cs], st, 0, 0, 0);
    }

    // ---- online softmax (exp2 domain), deferred rescale ----
    float pmax = st[0];
    #pragma unroll
    for (int r = 1; r < 16; ++r) pmax = fmaxf(pmax, st[r]);
    pmax = fmaxf(pmax, __shfl_xor(pmax, 32));
    if (!__all(pmax <= m_r + 8.f)) {
      const float mnew = fmaxf(m_r, pmax);
      const float scf = exp2f(m_r - mnew);
      #pragma unroll
      for (int ct = 0; ct < 8; ++ct) Ot[ct] *= scf;
      l_r *= scf; m_r = mnew;
    }
    float rs = 0.f;
    #pragma unroll
    for (int r = 0; r < 16; ++r) { st[r] = exp2f(st[r] - m_r); rs += st[r]; }
    rs += __shfl_xor(rs, 32);
    l_r += rs;

    // ---- P -> B-frags in-register: 8 cvt_pk + 4 permlane32_swap ----
    unsigned pk[8];
    #pragma unroll
    for (int p = 0; p < 8; ++p)
      asm("v_cvt_pk_bf16_f32 %0, %1, %2" : "=v"(pk[p]) : "v"(st[2 * p]), "v"(st[2 * p + 1]));
    asm volatile("v_permlane32_swap_b32 %0, %1" : "+v"(pk[0]), "+v"(pk[2]));
    asm volatile("v_permlane32_swap_b32 %0, %1" : "+v"(pk[1]), "+v"(pk[3]));
    asm volatile("v_permlane32_swap_b32 %0, %1" : "+v"(pk[4]), "+v"(pk[6]));
    asm volatile("v_permlane32_swap_b32 %0, %1" : "+v"(pk[5]), "+v"(pk[7]));
    int4 fA = {(int)pk[0], (int)pk[1], (int)pk[2], (int)pk[3]};
    int4 fB = {(int)pk[4], (int)pk[5], (int)pk[6], (int)pk[7]};
    const short8v pfA = __builtin_bit_cast(short8v, fA);
    const short8v pfB = __builtin_bit_cast(short8v, fB);

    // ---- O[256c][32i] += V * P ----
    const unsigned char* Vbuf = smem + 32768 + cur * 16384;
    #pragma unroll
    for (int ks = 0; ks < 2; ++ks) {
      const short8v pf = ks ? pfB : pfA;
      #pragma unroll
      for (int ct = 0; ct < 8; ++ct) {
        const short8v vf = *(const short8v*)(Vbuf + ((2 * ks + hi) * 256 + 32 * ct + ln) * 16);
        Ot[ct] = __builtin_amdgcn_mfma_f32_32x32x16_bf16(vf, pf, Ot[ct], 0, 0, 0);
      }
    }
    __syncthreads();
  }

  // ---- store partials: pO[half][b][c 256][i 4096] f32, pml[half][b][i][2] ----
  const size_t hb = (size_t)jh * 8 + b;
  float* po = pO + hb * 256 * (size_t)NPIX;
  const int i = i0 + 32 * w + ln;
  #pragma unroll
  for (int ct = 0; ct < 8; ++ct)
    #pragma unroll
    for (int r = 0; r < 16; ++r) {
      const int c = 32 * ct + (r & 3) + 8 * (r >> 2) + 4 * hi;
      po[(size_t)c * NPIX + i] = Ot[ct][r];
    }
  if (hi == 0) {
    pml[(hb * NPIX + i) * 2 + 0] = m_r;
    pml[(hb * NPIX + i) * 2 + 1] = l_r;
  }
}

// ---------------- combine halves -> aT [b][n][c] bf16 ----------------
__global__ __launch_bounds__(256)
void comb_k(const float* __restrict__ pO, const float* __restrict__ pml,
            unsigned short* __restrict__ aT) {
  __shared__ __align__(16) unsigned char tile[32768];   // [64 i][256 c] bf16, xor ((i&7)<<4)
  const int b  = blockIdx.y;
  const int i0 = blockIdx.x * 64;
  const int t  = threadIdx.x;
  const int i  = t & 63, cq = t >> 6;
  const size_t HALF = (size_t)8 * 256 * NPIX;

  const float m0 = pml[(((size_t)0 * 8 + b) * NPIX + i0 + i) * 2 + 0];
  const float l0 = pml[(((size_t)0 * 8 + b) * NPIX + i0 + i) * 2 + 1];
  const float m1 = pml[(((size_t)1 * 8 + b) * NPIX + i0 + i) * 2 + 0];
  const float l1 = pml[(((size_t)1 * 8 + b) * NPIX + i0 + i) * 2 + 1];
  const float M  = fmaxf(m0, m1);
  float w0 = exp2f(m0 - M), w1 = exp2f(m1 - M);
  const float rd = 1.0f / (w0 * l0 + w1 * l1);
  w0 *= rd; w1 *= rd;

  #pragma unroll 8
  for (int cc = 0; cc < 64; cc += 2) {
    const int c = cq * 64 + cc;
    const size_t off = ((size_t)b * 256 + c) * NPIX + i0 + i;
    const float va = pO[off] * w0 + pO[off + HALF] * w1;
    const float vbv = pO[off + NPIX] * w0 + pO[off + HALF + NPIX] * w1;
    unsigned pkv;
    asm("v_cvt_pk_bf16_f32 %0, %1, %2" : "=v"(pkv) : "v"(va), "v"(vbv));
    *(unsigned*)(tile + ((i * 512 + c * 2) ^ ((i & 7) << 4))) = pkv;
  }
  __syncthreads();
  unsigned short* dst = aT + ((size_t)b * NPIX + i0) * C_;
  #pragma unroll
  for (int u = 0; u < 8; ++u) {
    const int idx = u * 256 + t;
    const int ii = idx >> 5, cw = idx & 31;
    *(ush8*)(dst + (size_t)ii * C_ + cw * 8) =
        *(const ush8*)(tile + ((ii * 512 + cw * 16) ^ ((ii & 7) << 4)));
  }
}

// ---------------- proj GEMM: out = wp*aT + bp + x ----------------
__global__ __launch_bounds__(256, 2)
void proj_k(const float* __restrict__ Wp, const float* __restrict__ bp,
            const float* __restrict__ x, const unsigned short* __restrict__ aT,
            float* __restrict__ dout) {
  extern __shared__ __align__(16) unsigned char sm[];
  unsigned char* sX = sm;
  unsigned char* sW = sm + 32768;

  const int t = threadIdx.x;
  const int w = t >> 6, l = t & 63, hi = l >> 5, ln = l & 31;
  const int b  = blockIdx.z;
  const int n0 = blockIdx.x * 128;
  const int o0 = blockIdx.y * 128;

  const unsigned short* aTb = aT + (size_t)b * NPIX * C_;

  auto stage = [&](int s) {
    const int c0 = s * 64;
    unsigned char* Xb_ = sX + (s & 1) * 16384;
    unsigned char* Wb_ = sW + (s & 1) * 16384;
    #pragma unroll
    for (int i = 0; i < 8; ++i) {
      const int idx = i * 256 + t;
      const int o = idx >> 4;
      const int cq = (idx & 15) * 4;
      float4 v = *(const float4*)&Wp[(size_t)(o0 + o) * C_ + c0 + cq];
      ush4 h; h[0] = f2bf(v.x); h[1] = f2bf(v.y); h[2] = f2bf(v.z); h[3] = f2bf(v.w);
      *(ush4*)(Wb_ + ((o * 128 + cq * 2) ^ ((o & 7) << 4))) = h;
    }
    const int cs = t & 7, nb = t >> 3;
    #pragma unroll
    for (int r = 0; r < 4; ++r) {
      const int n = nb + 32 * r;
      short8v v = *(const short8v*)&aTb[(size_t)(n0 + n) * C_ + c0 + 8 * cs];
      *(short8v*)(Xb_ + ((n * 128 + 16 * cs) ^ ((n & 7) << 4))) = v;
    }
  };

  f32x16 acc[2][2];
  #pragma unroll
  for (int i = 0; i < 2; ++i)
    #pragma unroll
    for (int j = 0; j < 2; ++j)
      #pragma unroll
      for (int r = 0; r < 16; ++r) acc[i][j][r] = 0.f;

  stage(0);
  __syncthreads();
  for (int s = 0; s < 4; ++s) {
    if (s < 3) stage(s + 1);
    const unsigned char* Xb_ = sX + (s & 1) * 16384;
    const unsigned char* Wb_ = sW + (s & 1) * 16384;
    #pragma unroll
    for (int ks = 0; ks < 4; ++ks) {
      short8v xa[2], wf[2];
      #pragma unroll
      for (int mt = 0; mt < 2; ++mt) {
        const int n = 64 * (w >> 1) + 32 * mt + ln;
        xa[mt] = *(const short8v*)(Xb_ + ((n * 128 + 32 * ks + 16 * hi) ^ ((n & 7) << 4)));
        const int o = 64 * (w & 1) + 32 * mt + ln;
        wf[mt] = *(const short8v*)(Wb_ + ((o * 128 + 32 * ks + 16 * hi) ^ ((o & 7) << 4)));
      }
      #pragma unroll
      for (int mt = 0; mt < 2; ++mt)
        #pragma unroll
        for (int nt = 0; nt < 2; ++nt)
          acc[mt][nt] = __builtin_amdgcn_mfma_f32_32x32x16_bf16(wf[mt], xa[nt], acc[mt][nt], 0, 0, 0);
    }
    __syncthreads();
  }

  #pragma unroll
  for (int nt = 0; nt < 2; ++nt) {
    const int n = n0 + 64 * (w >> 1) + 32 * nt + ln;
    #pragma unroll
    for (int mt = 0; mt < 2; ++mt)
      #pragma unroll
      for (int r = 0; r < 16; ++r) {
        const int o = o0 + 64 * (w & 1) + 32 * mt + (r & 3) + 8 * (r >> 2) + 4 * hi;
        const size_t ad = ((size_t)b * C_ + o) * NPIX + n;
        dout[ad] = acc[mt][nt][r] + bp[o] + x[ad];
      }
  }
}

// ---------------- launch ----------------
extern "C" void kernel_launch(void* const* d_in, const int* in_sizes, int n_in,
                              void* d_out, int out_size, void* d_ws, size_t ws_size,
                              hipStream_t stream) {
  (void)in_sizes; (void)n_in; (void)out_size; (void)ws_size;
  const float* x      = (const float*)d_in[0];
  const float* norm_w = (const float*)d_in[1];
  const float* norm_b = (const float*)d_in[2];
  const float* wq = (const float*)d_in[3];
  const float* bq = (const float*)d_in[4];
  const float* wk = (const float*)d_in[5];
  const float* bk = (const float*)d_in[6];
  const float* wv = (const float*)d_in[7];
  const float* bv = (const float*)d_in[8];
  const float* wp = (const float*)d_in[9];
  const float* bp = (const float*)d_in[10];
  float* out = (float*)d_out;

  // ws (bytes): part 8K | stats @8K | qt @64K (16MB) | kt (+16M) | vb (+32M) | aT (+48M)
  //             | pO @64K+64M (64MB) | pml @64K+128M (512KB)
  unsigned char* ws = (unsigned char*)d_ws;
  float* part  = (float*)ws;
  float* stats = (float*)(ws + 8192);
  const size_t M16 = (size_t)16 * 1024 * 1024;
  unsigned short* qtb = (unsigned short*)(ws + 65536);
  unsigned short* ktb = (unsigned short*)(ws + 65536 + M16);
  unsigned short* vbb = (unsigned short*)(ws + 65536 + 2 * M16);
  unsigned short* aTb = (unsigned short*)(ws + 65536 + 3 * M16);
  float* pO  = (float*)(ws + 65536 + 4 * M16);
  float* pml = (float*)(ws + 65536 + 8 * M16);

  hipFuncSetAttribute((const void*)qkv_k,  hipFuncAttributeMaxDynamicSharedMemorySize, 67584);
  hipFuncSetAttribute((const void*)attn_k, hipFuncAttributeMaxDynamicSharedMemorySize, 65536);
  hipFuncSetAttribute((const void*)proj_k, hipFuncAttributeMaxDynamicSharedMemorySize, 67584);

  gn_part<<<1024, 256, 0, stream>>>((const float4*)x, part);
  gn_fin<<<1, 128, 0, stream>>>(part, stats);

  qkv_k<<<dim3(32, 6, B_), 256, 67584, stream>>>(wq, bq, wk, bk, wv, bv, x, stats,
                                                 norm_w, norm_b, qtb, ktb, vbb);

  attn_k<<<512, 256, 65536, stream>>>(qtb, ktb, vbb, pO, pml);

  comb_k<<<dim3(NPIX / 64, B_), 256, 0, stream>>>(pO, pml, aTb);

  proj_k<<<dim3(32, 2, B_), 256, 67584, stream>>>(wp, bp, x, aTb, out);
}